// Round 1
// baseline (810.203 us; speedup 1.0000x reference)
//
#include <hip/hip_runtime.h>
#include <stdint.h>

#define NE 50000   // entities
#define DD 128     // dim
#define RR 16      // relations
#define EE 50000   // edges per relation
#define NT 128     // node tile per block

typedef short  shortx8 __attribute__((ext_vector_type(8)));
typedef short  shortx4 __attribute__((ext_vector_type(4)));
typedef float  floatx4 __attribute__((ext_vector_type(4)));

__device__ __forceinline__ unsigned short f2bf(float f) {
    unsigned u = __float_as_uint(f);
    u += 0x7fffu + ((u >> 16) & 1u);   // RNE
    return (unsigned short)(u >> 16);
}
__device__ __forceinline__ float bf2f(unsigned short h) {
    return __uint_as_float(((unsigned)h) << 16);
}

__global__ void zero_i32(int* p, int n) {
    int i = blockIdx.x * 256 + threadIdx.x;
    if (i < n) p[i] = 0;
}

__global__ void cvt_bf16(const float* __restrict__ in, unsigned short* __restrict__ out, int n) {
    int i = blockIdx.x * 256 + threadIdx.x;
    if (i < n) out[i] = f2bf(in[i]);
}

__global__ void hist_k(const int* __restrict__ erow, int* __restrict__ counts) {
    int i = blockIdx.x * 256 + threadIdx.x;
    if (i < RR * EE) {
        int r = i / EE;
        atomicAdd(&counts[r * NE + erow[i]], 1);
    }
}

// one block per relation; builds row_ptr and leaves cursor (=counts) at row starts
__global__ void scan_k(int* __restrict__ counts, int* __restrict__ row_ptr) {
    int r = blockIdx.x;
    int t = threadIdx.x;                // 1024 threads
    const int CH = (NE + 1023) / 1024;  // 49
    int* c  = counts + r * NE;
    int* rp = row_ptr + r * (NE + 1);
    int base = t * CH;
    int s = 0;
    for (int i = 0; i < CH; i++) {
        int idx = base + i;
        if (idx < NE) s += c[idx];
    }
    __shared__ int sh[1024];
    sh[t] = s;
    __syncthreads();
    for (int off = 1; off < 1024; off <<= 1) {
        int add = (t >= off) ? sh[t - off] : 0;
        __syncthreads();
        sh[t] += add;
        __syncthreads();
    }
    int run = sh[t] - s;  // exclusive prefix
    for (int i = 0; i < CH; i++) {
        int idx = base + i;
        if (idx < NE) {
            int cnt = c[idx];
            rp[idx] = run;
            c[idx]  = run;   // cursor copy for fill_k
            run += cnt;
        }
    }
    if (t == 1023) rp[NE] = sh[1023];
}

__global__ void fill_k(const int* __restrict__ erow, const int* __restrict__ ecol,
                       const float* __restrict__ eval, int* __restrict__ cursor,
                       int2* __restrict__ edges) {
    int i = blockIdx.x * 256 + threadIdx.x;
    if (i < RR * EE) {
        int r = i / EE;
        int pos = atomicAdd(&cursor[r * NE + erow[i]], 1);
        int2 p;
        p.x = ecol[i];
        p.y = __float_as_int(eval[i]);
        edges[(size_t)r * EE + pos] = p;
    }
}

// Fused layer: out[n,i] = act( sum_r sum_j T_r[i,j] * (sum_{e:row=n} val_e * emb[col_e, j]) )
// Block: 256 threads = 4 waves, 128-node tile. LDS A = T_r (128x128 bf16, swizzled),
// LDS B = gathered acc (128 nodes x 128 dims bf16, swizzled). 16B-chunk XOR swizzle:
// chunk pc = lc ^ (row & 7) -> ds_read_b128 frag fetches are <=2-way conflicted (free).
template<bool FINAL>
__global__ __launch_bounds__(256, 2)
void layer_k(const unsigned short* __restrict__ embIn,
             const unsigned short* __restrict__ Tb,
             const int* __restrict__ row_ptr,
             const int2* __restrict__ edges,
             unsigned short* __restrict__ embOut,
             float* __restrict__ outF)
{
    __shared__ __align__(16) unsigned short At[128 * 128];
    __shared__ __align__(16) unsigned short Bt[128 * 128];

    const int t    = threadIdx.x;
    const int lane = t & 63;
    const int wave = t >> 6;
    const int colq = lane & 15;   // MFMA: m (A) / n (B) / col (D)
    const int q    = lane >> 4;   // MFMA quad
    const int n0   = blockIdx.x * NT;

    const int jgrp = t & 15;      // gather: which 8-dim chunk
    const int nsub = t >> 4;      // gather: node within 16-node group

    floatx4 acc[8][2];            // [i-tile][col-tile] accumulators (fp32)
    #pragma unroll
    for (int i = 0; i < 8; i++)
        #pragma unroll
        for (int c = 0; c < 2; c++)
            acc[i][c] = (floatx4){0.f, 0.f, 0.f, 0.f};

    for (int r = 0; r < RR; r++) {
        // ---- stage A: T_r -> LDS (swizzled 16B chunks), coalesced 16B loads
        #pragma unroll
        for (int it8 = 0; it8 < 8; it8++) {
            int g   = it8 * 256 + t;        // chunk id 0..2047
            int row = g >> 4;
            int lc  = g & 15;
            int pc  = lc ^ (row & 7);
            shortx8 v = *(const shortx8*)(Tb + ((size_t)r * (DD * DD) + row * DD + lc * 8));
            *(shortx8*)&At[row * 128 + pc * 8] = v;
        }
        // ---- stage B: CSR gather, 16 threads/node x 8 dims each, fp32 accumulate
        const int*  rp = row_ptr + r * (NE + 1);
        const int2* eg = edges + (size_t)r * EE;
        #pragma unroll 1
        for (int ch = 0; ch < 8; ch++) {
            int nl = ch * 16 + nsub;
            int n  = n0 + nl;
            float a8[8];
            #pragma unroll
            for (int j = 0; j < 8; j++) a8[j] = 0.f;
            if (n < NE) {
                int s = rp[n], e2 = rp[n + 1];
                for (int e = s; e < e2; e++) {
                    int2 p = eg[e];
                    float val = __int_as_float(p.y);
                    shortx8 ev = *(const shortx8*)(embIn + ((size_t)p.x * DD + jgrp * 8));
                    #pragma unroll
                    for (int j = 0; j < 8; j++)
                        a8[j] = fmaf(val, bf2f((unsigned short)ev[j]), a8[j]);
                }
            }
            shortx8 w;
            #pragma unroll
            for (int j = 0; j < 8; j++) w[j] = (short)f2bf(a8[j]);
            int pc = jgrp ^ (nl & 7);
            *(shortx8*)&Bt[nl * 128 + pc * 8] = w;
        }
        __syncthreads();

        // ---- MFMA: D[i,n] += sum_j A[i,j]*B[j,n]; A: m=lane&15,k=q*8+j; B sym; k tiles of 32
        #pragma unroll
        for (int kt = 0; kt < 4; kt++) {
            int lc = kt * 4 + q;                 // 16B chunk along k
            shortx8 bf[2];
            #pragma unroll
            for (int c = 0; c < 2; c++) {
                int nl = (wave * 2 + c) * 16 + colq;
                int pc = lc ^ (nl & 7);
                bf[c] = *(const shortx8*)&Bt[nl * 128 + pc * 8];
            }
            #pragma unroll
            for (int it = 0; it < 8; it++) {
                int mr = it * 16 + colq;
                int pc = lc ^ (mr & 7);
                shortx8 af = *(const shortx8*)&At[mr * 128 + pc * 8];
                acc[it][0] = __builtin_amdgcn_mfma_f32_16x16x32_bf16(af, bf[0], acc[it][0], 0, 0, 0);
                acc[it][1] = __builtin_amdgcn_mfma_f32_16x16x32_bf16(af, bf[1], acc[it][1], 0, 0, 0);
            }
        }
        __syncthreads();
    }

    // ---- epilogue. D layout: col = lane&15, row = q*4 + reg
    if (!FINAL) {
        #pragma unroll
        for (int c = 0; c < 2; c++) {
            int n = n0 + (wave * 2 + c) * 16 + colq;
            if (n < NE) {
                #pragma unroll
                for (int it = 0; it < 8; it++) {
                    shortx4 w;
                    #pragma unroll
                    for (int g = 0; g < 4; g++) {
                        float v = acc[it][c][g];
                        v = v > 0.f ? v : 0.f;
                        w[g] = (short)f2bf(v);
                    }
                    *(shortx4*)(embOut + ((size_t)n * DD + it * 16 + q * 4)) = w;
                }
            }
        }
    } else {
        #pragma unroll
        for (int c = 0; c < 2; c++) {
            float ss = 0.f;
            #pragma unroll
            for (int it = 0; it < 8; it++)
                #pragma unroll
                for (int g = 0; g < 4; g++) {
                    float v = acc[it][c][g];
                    v = v > 0.f ? v : 0.f;
                    acc[it][c][g] = v;
                    ss += v * v;
                }
            // lanes l, l^16, l^32, l^48 hold the 4 row-quads of the same node
            ss += __shfl_xor(ss, 16, 64);
            ss += __shfl_xor(ss, 32, 64);
            float scale = 1.f / fmaxf(sqrtf(ss), 1e-12f);
            int n = n0 + (wave * 2 + c) * 16 + colq;
            if (n < NE) {
                #pragma unroll
                for (int it = 0; it < 8; it++) {
                    floatx4 v4;
                    #pragma unroll
                    for (int g = 0; g < 4; g++) v4[g] = acc[it][c][g] * scale;
                    *(floatx4*)(outF + ((size_t)n * DD + it * 16 + q * 4)) = v4;
                }
            }
        }
    }
}

extern "C" void kernel_launch(void* const* d_in, const int* in_sizes, int n_in,
                              void* d_out, int out_size, void* d_ws, size_t ws_size,
                              hipStream_t stream)
{
    const float* ent_emb   = (const float*)d_in[0];   // [NE, DD] fp32
    const float* rel_trans = (const float*)d_in[1];   // [RR, DD, DD] fp32
    const float* edge_val  = (const float*)d_in[2];   // [RR, EE] fp32
    const int*   edge_row  = (const int*)d_in[3];     // [RR, EE] int32
    const int*   edge_col  = (const int*)d_in[4];     // [RR, EE] int32
    float* out = (float*)d_out;                       // [NE, DD] fp32

    char* ws = (char*)d_ws;
    size_t off = 0;
    int* counts = (int*)(ws + off);            off += (size_t)RR * NE * 4;        // hist -> cursor
    int* row_ptr = (int*)(ws + off);           off += (size_t)RR * (NE + 1) * 4;
    int2* edges = (int2*)(ws + off);           off += (size_t)RR * EE * 8;        // (col, val)
    unsigned short* Tb   = (unsigned short*)(ws + off); off += (size_t)RR * DD * DD * 2;
    unsigned short* embA = (unsigned short*)(ws + off); off += (size_t)NE * DD * 2;
    unsigned short* embB = (unsigned short*)(ws + off); off += (size_t)NE * DD * 2;
    // total ~38.9 MB

    zero_i32<<<(RR * NE + 255) / 256, 256, 0, stream>>>(counts, RR * NE);
    cvt_bf16<<<(RR * DD * DD + 255) / 256, 256, 0, stream>>>(rel_trans, Tb, RR * DD * DD);
    cvt_bf16<<<(NE * DD + 255) / 256, 256, 0, stream>>>(ent_emb, embA, NE * DD);
    hist_k<<<(RR * EE + 255) / 256, 256, 0, stream>>>(edge_row, counts);
    scan_k<<<RR, 1024, 0, stream>>>(counts, row_ptr);
    fill_k<<<(RR * EE + 255) / 256, 256, 0, stream>>>(edge_row, edge_col, edge_val, counts, edges);

    int nb = (NE + NT - 1) / NT;  // 391
    layer_k<false><<<nb, 256, 0, stream>>>(embA, Tb, row_ptr, edges, embB, nullptr);
    layer_k<true ><<<nb, 256, 0, stream>>>(embB, Tb, row_ptr, edges, nullptr, out);
}

// Round 2
// 422.984 us; speedup vs baseline: 1.9154x; 1.9154x over previous
//
#include <hip/hip_runtime.h>
#include <stdint.h>

#define NE 50000   // entities
#define DD 128     // dim
#define RR 16      // relations
#define EE 50000   // edges per relation
#define NT 128     // node tile per block
#define NTOT (RR * NE)                 // 800000 flat (r,n) rows
#define SCAN_BLK 4096
#define NSCAN ((NTOT + SCAN_BLK - 1) / SCAN_BLK)   // 196

typedef short  shortx8 __attribute__((ext_vector_type(8)));
typedef short  shortx4 __attribute__((ext_vector_type(4)));
typedef float  floatx4 __attribute__((ext_vector_type(4)));

__device__ __forceinline__ unsigned short f2bf(float f) {
    unsigned u = __float_as_uint(f);
    u += 0x7fffu + ((u >> 16) & 1u);   // RNE
    return (unsigned short)(u >> 16);
}
__device__ __forceinline__ float bf2f(unsigned short h) {
    return __uint_as_float(((unsigned)h) << 16);
}

__global__ void zero_i32(int* p, int n) {
    int i = blockIdx.x * 256 + threadIdx.x;
    if (i < n) p[i] = 0;
}

__global__ void cvt_bf16x4(const float4* __restrict__ in, shortx4* __restrict__ out, int n4) {
    int i = blockIdx.x * 256 + threadIdx.x;
    if (i < n4) {
        float4 v = in[i];
        shortx4 w;
        w[0] = (short)f2bf(v.x); w[1] = (short)f2bf(v.y);
        w[2] = (short)f2bf(v.z); w[3] = (short)f2bf(v.w);
        out[i] = w;
    }
}

__global__ void hist_k(const int* __restrict__ erow, int* __restrict__ counts) {
    int i = blockIdx.x * 256 + threadIdx.x;
    if (i < NTOT) {
        int r = i / EE;
        atomicAdd(&counts[r * NE + erow[i]], 1);
    }
}

// ---- 3-phase flat exclusive scan over counts[NTOT] -> rp[NTOT+1], cursor(=counts)
__global__ void scanA(const int* __restrict__ c, int* __restrict__ bsum) {
    int b = blockIdx.x, t = threadIdx.x;
    int base = b * SCAN_BLK + t * 16;
    int s = 0;
    #pragma unroll
    for (int i = 0; i < 16; i++) {
        int idx = base + i;
        if (idx < NTOT) s += c[idx];
    }
    __shared__ int sh[256];
    sh[t] = s;
    __syncthreads();
    for (int off = 128; off > 0; off >>= 1) {
        if (t < off) sh[t] += sh[t + off];
        __syncthreads();
    }
    if (t == 0) bsum[b] = sh[0];
}

__global__ void scanB(int* __restrict__ bsum) {
    int t = threadIdx.x;
    int v = (t < NSCAN) ? bsum[t] : 0;
    __shared__ int sh[256];
    sh[t] = v;
    __syncthreads();
    for (int off = 1; off < 256; off <<= 1) {
        int add = (t >= off) ? sh[t - off] : 0;
        __syncthreads();
        sh[t] += add;
        __syncthreads();
    }
    if (t < NSCAN) bsum[t] = sh[t] - v;   // exclusive
}

__global__ void scanC(int* __restrict__ counts, int* __restrict__ rp,
                      const int* __restrict__ bsum) {
    int b = blockIdx.x, t = threadIdx.x;
    int base = b * SCAN_BLK + t * 16;
    int vals[16];
    int s = 0;
    #pragma unroll
    for (int i = 0; i < 16; i++) {
        int idx = base + i;
        vals[i] = (idx < NTOT) ? counts[idx] : 0;
        s += vals[i];
    }
    __shared__ int sh[256];
    sh[t] = s;
    __syncthreads();
    for (int off = 1; off < 256; off <<= 1) {
        int add = (t >= off) ? sh[t - off] : 0;
        __syncthreads();
        sh[t] += add;
        __syncthreads();
    }
    int run = bsum[b] + sh[t] - s;
    #pragma unroll
    for (int i = 0; i < 16; i++) {
        int idx = base + i;
        if (idx < NTOT) {
            int cv = vals[i];
            rp[idx]     = run;
            counts[idx] = run;   // cursor for fill_k
            run += cv;
            if (idx == NTOT - 1) rp[NTOT] = run;
        }
    }
}

__global__ void fill_k(const int* __restrict__ erow, const int* __restrict__ ecol,
                       const float* __restrict__ eval, int* __restrict__ cursor,
                       int2* __restrict__ edges) {
    int i = blockIdx.x * 256 + threadIdx.x;
    if (i < NTOT) {
        int r = i / EE;
        int pos = atomicAdd(&cursor[r * NE + erow[i]], 1);
        int2 p;
        p.x = ecol[i];
        p.y = __float_as_int(eval[i]);
        edges[pos] = p;
    }
}

// Fused layer: out[n,i] = act( sum_r sum_j T_r[i,j] * (sum_{e:row=n} val_e * emb[col_e, j]) )
// 512 threads = 8 waves, 128-node tile, 2 blocks/CU (LDS 66 KB).
// Gather: 8 threads/node x 2 chunks, 2 phased passes (rp+entry loads hoisted).
// MFMA: wave (wi,wn) owns D[i in wi*32..+32][n in wn*64..+64]; acc[2][4] floatx4.
template<bool FINAL>
__global__ __launch_bounds__(512, 4)
void layer_k(const unsigned short* __restrict__ embIn,
             const unsigned short* __restrict__ Tb,
             const int* __restrict__ rp,
             const int2* __restrict__ eg,
             unsigned short* __restrict__ embOut,
             float* __restrict__ outF)
{
    __shared__ __align__(16) unsigned short At[128 * 128];
    __shared__ __align__(16) unsigned short Bt[128 * 128];
    __shared__ float ssred[4][128];

    const int t    = threadIdx.x;
    const int lane = t & 63;
    const int w    = t >> 6;       // 0..7
    const int wi   = w >> 1;       // i block (x32)
    const int wn   = w & 1;        // n block (x64)
    const int colq = lane & 15;
    const int q    = lane >> 4;
    const int n0   = blockIdx.x * NT;

    const int nsub = t >> 3;       // 0..63: node within pass
    const int dgrp = t & 7;        // 8-dim chunk group (chunks dgrp, dgrp+8)

    floatx4 acc[2][4];
    #pragma unroll
    for (int a = 0; a < 2; a++)
        #pragma unroll
        for (int c = 0; c < 4; c++)
            acc[a][c] = (floatx4){0.f, 0.f, 0.f, 0.f};

    for (int r = 0; r < RR; r++) {
        // ---- stage A: T_r -> LDS (swizzled 16B chunks)
        #pragma unroll
        for (int it = 0; it < 4; it++) {
            int g   = it * 512 + t;          // chunk 0..2047
            int row = g >> 4;
            int lc  = g & 15;
            int pc  = (lc & 8) | ((lc ^ row) & 7);
            shortx8 v = *(const shortx8*)(Tb + ((size_t)r * (DD * DD) + row * DD + lc * 8));
            *(shortx8*)&At[row * 128 + pc * 8] = v;
        }

        // ---- gather: phase all rp + first/second entry loads, then emb loads
        int s_[2], c_[2];
        #pragma unroll
        for (int p = 0; p < 2; p++) {
            int nl = p * 64 + nsub;
            int n  = n0 + nl;
            int sE = 0, eE = 0;
            if (n < NE) { int b = r * NE + n; sE = rp[b]; eE = rp[b + 1]; }
            s_[p] = sE; c_[p] = eE - sE;
        }
        int2 e0[2], e1[2];
        #pragma unroll
        for (int p = 0; p < 2; p++) {
            e0[p] = make_int2(0, 0); e1[p] = make_int2(0, 0);
            if (c_[p] > 0) e0[p] = eg[s_[p]];
            if (c_[p] > 1) e1[p] = eg[s_[p] + 1];
        }
        #pragma unroll
        for (int p = 0; p < 2; p++) {
            float a0[8], a1[8];
            #pragma unroll
            for (int j = 0; j < 8; j++) { a0[j] = 0.f; a1[j] = 0.f; }
            if (c_[p] > 0) {
                float v = __int_as_float(e0[p].y);
                const unsigned short* rw = embIn + (size_t)e0[p].x * DD;
                shortx8 q0 = *(const shortx8*)(rw + dgrp * 8);
                shortx8 q1 = *(const shortx8*)(rw + dgrp * 8 + 64);
                #pragma unroll
                for (int j = 0; j < 8; j++) {
                    a0[j] = fmaf(v, bf2f((unsigned short)q0[j]), a0[j]);
                    a1[j] = fmaf(v, bf2f((unsigned short)q1[j]), a1[j]);
                }
            }
            if (c_[p] > 1) {
                float v = __int_as_float(e1[p].y);
                const unsigned short* rw = embIn + (size_t)e1[p].x * DD;
                shortx8 q0 = *(const shortx8*)(rw + dgrp * 8);
                shortx8 q1 = *(const shortx8*)(rw + dgrp * 8 + 64);
                #pragma unroll
                for (int j = 0; j < 8; j++) {
                    a0[j] = fmaf(v, bf2f((unsigned short)q0[j]), a0[j]);
                    a1[j] = fmaf(v, bf2f((unsigned short)q1[j]), a1[j]);
                }
            }
            int ee = s_[p] + c_[p];
            for (int k = s_[p] + 2; k < ee; k++) {   // rare (deg>=3)
                int2 E = eg[k];
                float v = __int_as_float(E.y);
                const unsigned short* rw = embIn + (size_t)E.x * DD;
                shortx8 q0 = *(const shortx8*)(rw + dgrp * 8);
                shortx8 q1 = *(const shortx8*)(rw + dgrp * 8 + 64);
                #pragma unroll
                for (int j = 0; j < 8; j++) {
                    a0[j] = fmaf(v, bf2f((unsigned short)q0[j]), a0[j]);
                    a1[j] = fmaf(v, bf2f((unsigned short)q1[j]), a1[j]);
                }
            }
            int nl = p * 64 + nsub;
            shortx8 w0, w1;
            #pragma unroll
            for (int j = 0; j < 8; j++) { w0[j] = (short)f2bf(a0[j]); w1[j] = (short)f2bf(a1[j]); }
            int lcA = dgrp;
            int pcA = (lcA & 8) | ((lcA ^ nl) & 7);
            *(shortx8*)&Bt[nl * 128 + pcA * 8] = w0;
            int lcB = dgrp + 8;
            int pcB = (lcB & 8) | ((lcB ^ nl) & 7);
            *(shortx8*)&Bt[nl * 128 + pcB * 8] = w1;
        }
        __syncthreads();

        // ---- MFMA
        #pragma unroll
        for (int kt = 0; kt < 4; kt++) {
            int lc = kt * 4 + q;
            shortx8 af[2], bf[4];
            #pragma unroll
            for (int it2 = 0; it2 < 2; it2++) {
                int row = wi * 32 + it2 * 16 + colq;
                int pc  = (lc & 8) | ((lc ^ row) & 7);
                af[it2] = *(const shortx8*)&At[row * 128 + pc * 8];
            }
            #pragma unroll
            for (int c = 0; c < 4; c++) {
                int nl = wn * 64 + c * 16 + colq;
                int pc = (lc & 8) | ((lc ^ nl) & 7);
                bf[c] = *(const shortx8*)&Bt[nl * 128 + pc * 8];
            }
            #pragma unroll
            for (int it2 = 0; it2 < 2; it2++)
                #pragma unroll
                for (int c = 0; c < 4; c++)
                    acc[it2][c] = __builtin_amdgcn_mfma_f32_16x16x32_bf16(af[it2], bf[c], acc[it2][c], 0, 0, 0);
        }
        __syncthreads();
    }

    // ---- epilogue. D: col = lane&15 -> n, row = q*4+reg -> i (within wave tile)
    if (!FINAL) {
        #pragma unroll
        for (int c = 0; c < 4; c++) {
            int n = n0 + wn * 64 + c * 16 + colq;
            if (n < NE) {
                #pragma unroll
                for (int it2 = 0; it2 < 2; it2++) {
                    shortx4 wv;
                    #pragma unroll
                    for (int g = 0; g < 4; g++) {
                        float v = acc[it2][c][g];
                        v = v > 0.f ? v : 0.f;
                        wv[g] = (short)f2bf(v);
                    }
                    *(shortx4*)(embOut + ((size_t)n * DD + wi * 32 + it2 * 16 + q * 4)) = wv;
                }
            }
        }
    } else {
        float ssc[4];
        #pragma unroll
        for (int c = 0; c < 4; c++) {
            float ss = 0.f;
            #pragma unroll
            for (int it2 = 0; it2 < 2; it2++)
                #pragma unroll
                for (int g = 0; g < 4; g++) {
                    float v = acc[it2][c][g];
                    v = v > 0.f ? v : 0.f;
                    acc[it2][c][g] = v;
                    ss += v * v;
                }
            ss += __shfl_xor(ss, 16, 64);   // reduce over q quads
            ss += __shfl_xor(ss, 32, 64);
            ssc[c] = ss;
        }
        if (q == 0) {
            #pragma unroll
            for (int c = 0; c < 4; c++)
                ssred[wi][wn * 64 + c * 16 + colq] = ssc[c];
        }
        __syncthreads();
        #pragma unroll
        for (int c = 0; c < 4; c++) {
            int nl = wn * 64 + c * 16 + colq;
            float tot = ssred[0][nl] + ssred[1][nl] + ssred[2][nl] + ssred[3][nl];
            float scale = 1.f / fmaxf(sqrtf(tot), 1e-12f);
            int n = n0 + nl;
            if (n < NE) {
                #pragma unroll
                for (int it2 = 0; it2 < 2; it2++) {
                    floatx4 v4;
                    #pragma unroll
                    for (int g = 0; g < 4; g++) v4[g] = acc[it2][c][g] * scale;
                    *(floatx4*)(outF + ((size_t)n * DD + wi * 32 + it2 * 16 + q * 4)) = v4;
                }
            }
        }
    }
}

static inline size_t align256(size_t x) { return (x + 255) & ~(size_t)255; }

extern "C" void kernel_launch(void* const* d_in, const int* in_sizes, int n_in,
                              void* d_out, int out_size, void* d_ws, size_t ws_size,
                              hipStream_t stream)
{
    const float* ent_emb   = (const float*)d_in[0];   // [NE, DD] fp32
    const float* rel_trans = (const float*)d_in[1];   // [RR, DD, DD] fp32
    const float* edge_val  = (const float*)d_in[2];   // [RR, EE] fp32
    const int*   edge_row  = (const int*)d_in[3];     // [RR, EE] int32
    const int*   edge_col  = (const int*)d_in[4];     // [RR, EE] int32
    float* out = (float*)d_out;                       // [NE, DD] fp32

    char* ws = (char*)d_ws;
    size_t off = 0;
    int* counts = (int*)(ws + off);  off = align256(off + (size_t)NTOT * 4);        // hist -> cursor
    int* rpf    = (int*)(ws + off);  off = align256(off + ((size_t)NTOT + 1) * 4);  // flat row_ptr
    int* bsum   = (int*)(ws + off);  off = align256(off + 256 * 4);
    int2* edges = (int2*)(ws + off); off = align256(off + (size_t)NTOT * 8);
    unsigned short* Tb   = (unsigned short*)(ws + off); off = align256(off + (size_t)RR * DD * DD * 2);
    unsigned short* embA = (unsigned short*)(ws + off); off = align256(off + (size_t)NE * DD * 2);
    unsigned short* embB = (unsigned short*)(ws + off); off = align256(off + (size_t)NE * DD * 2);
    // total ~39 MB

    zero_i32<<<(NTOT + 255) / 256, 256, 0, stream>>>(counts, NTOT);
    cvt_bf16x4<<<((RR * DD * DD / 4) + 255) / 256, 256, 0, stream>>>(
        (const float4*)rel_trans, (shortx4*)Tb, RR * DD * DD / 4);
    cvt_bf16x4<<<((NE * DD / 4) + 255) / 256, 256, 0, stream>>>(
        (const float4*)ent_emb, (shortx4*)embA, NE * DD / 4);
    hist_k<<<(NTOT + 255) / 256, 256, 0, stream>>>(edge_row, counts);
    scanA<<<NSCAN, 256, 0, stream>>>(counts, bsum);
    scanB<<<1, 256, 0, stream>>>(bsum);
    scanC<<<NSCAN, 256, 0, stream>>>(counts, rpf, bsum);
    fill_k<<<(NTOT + 255) / 256, 256, 0, stream>>>(edge_row, edge_col, edge_val, counts, edges);

    int nb = (NE + NT - 1) / NT;  // 391
    layer_k<false><<<nb, 512, 0, stream>>>(embA, Tb, rpf, edges, embB, nullptr);
    layer_k<true ><<<nb, 512, 0, stream>>>(embB, Tb, rpf, edges, nullptr, out);
}